// Round 10
// baseline (8823.566 us; speedup 1.0000x reference)
//
#include <hip/hip_runtime.h>
#include <math.h>

#define TT 512
#define BB 128
#define KK 9

// ---------------------------------------------------------------------------
// fast activations: v_exp_f32 / v_rcp_f32 based (~1 ulp each)
// ---------------------------------------------------------------------------
__device__ __forceinline__ float fast_sigmoid(float x) {
    const float LOG2E = 1.4426950408889634f;
    float e = __builtin_amdgcn_exp2f(-x * LOG2E);
    return __builtin_amdgcn_rcpf(1.0f + e);
}
__device__ __forceinline__ float fast_tanh(float x) {
    const float LOG2E = 1.4426950408889634f;
    float a = fabsf(x);
    float e = __builtin_amdgcn_exp2f(-2.0f * a * LOG2E);   // in (0,1]
    float t = (1.0f - e) * __builtin_amdgcn_rcpf(1.0f + e);
    return copysignf(t, x);
}

// all threads spin until (dir,slot) has all 4 gate tiles published
__device__ __forceinline__ void wait_flag(const unsigned* f, int idx) {
    while (__hip_atomic_load(&f[idx], __ATOMIC_ACQUIRE,
                             __HIP_MEMORY_SCOPE_AGENT) < 4u)
        __builtin_amdgcn_s_sleep(1);
}

// ---------------------------------------------------------------------------
// MEGA (R18 = R17 + deadlock-proofing): G and L fused into ONE dispatch.
// R9 failure analysis: __launch_bounds__(512,2) permits up to 256 VGPR ->
// merged kernel could exceed 128 VGPR -> 1 block/CU -> only 256 resident
// slots -> all could be L-role spinners -> no G-role block ever runs ->
// HANG. Fix: __launch_bounds__(512,4) caps VGPR at 128 (both roles
// measured 84 standalone) -> 2 blocks/CU GUARANTEED (LDS 62976x2=123KB
// <= 160KB) -> >=256 slots always host G-role blocks, which never wait
// and retire -> progress guaranteed; worst case = serial order, never
// deadlock.
// Roles: blocks 0..255 = L (grid-first, resident from t=0); blocks
// 256.. = G (C*8: 4 gate tiles x 2 dirs x C timesteps; y/dir in low
// bits, dir1 slots reversed so flags complete in L's consumption order).
// Sync: per-(dir,slot) flag zeroed by hipMemsetAsync before the kernel
// (replay/poison-proof); G publishes via syncthreads (vmcnt drain) +
// threadfence + release-add (pattern proven by emB sync since R11);
// L acquire-spins in the post-barrier fire-and-forget slot.
// ---------------------------------------------------------------------------
__global__ __launch_bounds__(512, 4) void mega(
    const int* __restrict__ x, const float* __restrict__ emb,
    const float* __restrict__ w_ih_f, const float* __restrict__ w_ih_b,
    const float* __restrict__ b_ih_f, const float* __restrict__ b_hh_f,
    const float* __restrict__ b_ih_b, const float* __restrict__ b_hh_b,
    float* __restrict__ buf_f, float* __restrict__ buf_b,
    const float* __restrict__ w_hh_f, const float* __restrict__ w_hh_b,
    float* __restrict__ h_all,
    float* __restrict__ h_state, float* __restrict__ c_state,
    const float* __restrict__ W_tag, const float* __restrict__ b_tag,
    const float* __restrict__ start_trans, const float* __restrict__ end_trans,
    const float* __restrict__ trans,
    float* __restrict__ emB, unsigned* __restrict__ flags,
    unsigned* __restrict__ gflags, int* __restrict__ out,
    int t0f, int t0b, int C, int init, int tail)
{
    // shared pool (62976 B, same as proven L kernel); G-role aliases
    // its As/Bs (2 x 32*132 floats) onto h_tile.
    __shared__ __align__(16) float h_lds[2][128];    // 1 KB
    __shared__ __align__(16) float wt_s[KK * 132];   // 4.6 KB
    __shared__ __align__(16) float em_s[TT * KK];    // 18.4 KB
    __shared__ __align__(16) float h_tile[64 * 132]; // 33.8 KB (G: As|Bs)
    __shared__ unsigned char bp[TT][KK];             // 4.6 KB

    if (blockIdx.x >= 256) {
        // ================= G-role: R14 input projection (proven math) ======
        const int gx   = blockIdx.x - 256;
        const int y    = gx & 3;
        const int dir  = (gx >> 2) & 1;
        const int sg   = gx >> 3;                 // 0..C-1 in schedule order
        const int slot = dir ? (C - 1 - sg) : sg; // production = consumption order
        const int n0   = y * 128;
        const int t    = (dir ? t0b : t0f) + slot;
        const float* w  = dir ? w_ih_b : w_ih_f;
        const float* bi = dir ? b_ih_b : b_ih_f;
        const float* bh = dir ? b_hh_b : b_hh_f;
        float* dst = dir ? buf_b : buf_f;

        float* As = h_tile;            // [k*132 + row], 4224 floats
        float* Bs = h_tile + 4224;     // [k*132 + row], 4224 floats

        const int tid    = threadIdx.x;
        const bool active = tid < 256;
        const int lrow = (tid & 255) >> 3;        // 0..31
        const int k4   = (tid & 7) * 4;           // 0..28
        const int tx   = tid & 15;
        const int ty   = (tid & 255) >> 4;

        int tokr[4];
        float4 aS[4], bS[4];
        float acc[8][8];
        if (active) {
            #pragma unroll
            for (int p = 0; p < 4; p++) tokr[p] = x[(p * 32 + lrow) * TT + t];
            #pragma unroll
            for (int i = 0; i < 8; i++)
                #pragma unroll
                for (int j = 0; j < 8; j++) acc[i][j] = 0.0f;
            #pragma unroll
            for (int p = 0; p < 4; p++) {
                aS[p] = *(const float4*)(emb + (size_t)tokr[p] * 128 + k4);
                bS[p] = *(const float4*)(w + (size_t)(n0 + p * 32 + lrow) * 128 + k4);
            }
        }

        for (int kc = 0; kc < 128; kc += 32) {
            __syncthreads();                 // prev chunk's reads done (all 512)
            if (active) {
                #pragma unroll
                for (int p = 0; p < 4; p++) {
                    const int row = p * 32 + lrow;
                    As[(k4 + 0) * 132 + row] = aS[p].x;
                    As[(k4 + 1) * 132 + row] = aS[p].y;
                    As[(k4 + 2) * 132 + row] = aS[p].z;
                    As[(k4 + 3) * 132 + row] = aS[p].w;
                    Bs[(k4 + 0) * 132 + row] = bS[p].x;
                    Bs[(k4 + 1) * 132 + row] = bS[p].y;
                    Bs[(k4 + 2) * 132 + row] = bS[p].z;
                    Bs[(k4 + 3) * 132 + row] = bS[p].w;
                }
            }
            __syncthreads();                 // staging visible (all 512)
            if (active) {
                if (kc + 32 < 128) {         // prefetch next chunk
                    #pragma unroll
                    for (int p = 0; p < 4; p++) {
                        aS[p] = *(const float4*)(emb + (size_t)tokr[p] * 128 + kc + 32 + k4);
                        bS[p] = *(const float4*)(w + (size_t)(n0 + p * 32 + lrow) * 128 + kc + 32 + k4);
                    }
                }
                #pragma unroll 8
                for (int k = 0; k < 32; k++) {
                    float4 af0 = *(const float4*)&As[k * 132 + ty * 8];
                    float4 af1 = *(const float4*)&As[k * 132 + ty * 8 + 4];
                    float4 bf0 = *(const float4*)&Bs[k * 132 + tx * 4];
                    float4 bf1 = *(const float4*)&Bs[k * 132 + 64 + tx * 4];
                    float a_[8] = {af0.x, af0.y, af0.z, af0.w, af1.x, af1.y, af1.z, af1.w};
                    float b_[8] = {bf0.x, bf0.y, bf0.z, bf0.w, bf1.x, bf1.y, bf1.z, bf1.w};
                    #pragma unroll
                    for (int i = 0; i < 8; i++)
                        #pragma unroll
                        for (int j = 0; j < 8; j++)
                            acc[i][j] += a_[i] * b_[j];
                }
            }
        }

        if (active) {
            const int nb0 = n0 + tx * 4;
            const int nb1 = n0 + 64 + tx * 4;
            float bias[8];
            #pragma unroll
            for (int j = 0; j < 4; j++) {
                bias[j]     = bi[nb0 + j] + bh[nb0 + j];
                bias[4 + j] = bi[nb1 + j] + bh[nb1 + j];
            }
            #pragma unroll
            for (int i = 0; i < 8; i++) {
                int brow = ty * 8 + i;
                float* o = dst + ((size_t)slot * 128 + brow) * 512;
                float4 v0, v1;
                v0.x = acc[i][0] + bias[0]; v0.y = acc[i][1] + bias[1];
                v0.z = acc[i][2] + bias[2]; v0.w = acc[i][3] + bias[3];
                v1.x = acc[i][4] + bias[4]; v1.y = acc[i][5] + bias[5];
                v1.z = acc[i][6] + bias[6]; v1.w = acc[i][7] + bias[7];
                *(float4*)(o + nb0) = v0;
                *(float4*)(o + nb1) = v1;
            }
        }
        __syncthreads();                     // all stores drained (vmcnt 0)
        if (threadIdx.x == 0) {
            __threadfence();                 // agent-scope visibility
            __hip_atomic_fetch_add(&gflags[dir * C + slot], 1u,
                                   __ATOMIC_RELEASE, __HIP_MEMORY_SCOPE_AGENT);
        }
        return;
    }

    // ================= L-role: proven R5 LSTM + tail (spin-guarded x) ======
    const int dir = blockIdx.x >> 7;
    const int b   = blockIdx.x & 127;
    const int j   = threadIdx.x;
    const int w_  = j >> 6;          // wave id 0..7
    const int l   = j & 63;
    const int m   = l >> 2;          // group 0..15
    const int q   = l & 3;           // gate: 0=i 1=f 2=g 3=o
    const int k   = w_ * 16 + m;     // h index 0..127
    const int r   = q * 128 + k;     // gate row in [0,512)

    unsigned snap = 0u;
    if (tail && dir == 0 && j == 0)
        snap = __hip_atomic_load(&flags[b], __ATOMIC_RELAXED, __HIP_MEMORY_SCOPE_AGENT);

    const float* whh = dir ? w_hh_b : w_hh_f;
    float wR[128];
    #pragma unroll
    for (int qq = 0; qq < 32; qq++) {
        float4 v = *(const float4*)(whh + (size_t)r * 128 + qq * 4);
        wR[4*qq+0] = v.x; wR[4*qq+1] = v.y; wR[4*qq+2] = v.z; wR[4*qq+3] = v.w;
    }

    float c;
    if (init) {
        c = 0.0f;
        if (q == 0) h_lds[0][k] = 0.0f;
    } else {
        c = c_state[((size_t)dir * 128 + b) * 128 + k];
        if (q == 0) h_lds[0][k] = h_state[((size_t)dir * 128 + b) * 128 + k];
    }
    __syncthreads();                     // h_lds[0] visible

    const float* buf = dir ? buf_b : buf_f;
    const int t0     = dir ? t0b : t0f;
    const int  tl0   = dir ? (C - 1) : 0;
    const long lstep = dir ? -(long)(128 * 512) : (long)(128 * 512);
    const int  fbase = dir * C;

    const float* xp = buf + ((size_t)tl0 * 128 + b) * 512 + r;
    wait_flag(gflags, fbase + tl0);      // first slot ready
    float xw = *xp;
    float h_reg = 0.0f;

    float* hdst = h_all + (size_t)(dir * BB + b) * TT * 128;   // private region

    for (int s = 0; s < C; s++) {
        const int t = t0 + (dir ? (C - 1 - s) : s);
        const int p = s & 1;
        const float* hprev = h_lds[p];

        float a0 = 0.f, a1 = 0.f, a2 = 0.f, a3 = 0.f;
        #pragma unroll
        for (int qq = 0; qq < 32; qq++) {
            float4 h4 = *(const float4*)&hprev[4 * qq];
            a0 += wR[4*qq+0] * h4.x;
            a1 += wR[4*qq+1] * h4.y;
            a2 += wR[4*qq+2] * h4.z;
            a3 += wR[4*qq+3] * h4.w;
        }
        float pre = xw + ((a0 + a1) + (a2 + a3));

        float act = (q == 2) ? fast_tanh(pre) : fast_sigmoid(pre);

        float f_ = __shfl_xor(act, 1);   // q0 <- q1 (f)
        float g_ = __shfl_xor(act, 2);   // q0 <- q2 (g)
        float o_ = __shfl_xor(act, 3);   // q0 <- q3 (o)

        c = f_ * c + act * g_;           // act == i on q0
        h_reg = o_ * fast_tanh(c);
        if (q == 0) h_lds[p ^ 1][k] = h_reg;

        __syncthreads();                 // h_t visible to all waves

        // post-barrier fire-and-forget slot
        if (s + 1 < C) {
            const int nslot = dir ? (C - 2 - s) : (s + 1);
            wait_flag(gflags, fbase + nslot);   // producer done for next slot
            xp += lstep; xw = *xp;
        }
        if (q == 0)
            hdst[(size_t)t * 128 + k] = h_reg;
    }

    if (q == 0) {
        h_state[((size_t)dir * 128 + b) * 128 + k] = h_reg;
        c_state[((size_t)dir * 128 + b) * 128 + k] = c;
    }

    if (!tail) return;                   // chunked path: only last round decodes

    // ---- phase C: staged, coalesced emission GEMM -------------------------
    for (int f = j; f < KK * 128; f += 512)
        wt_s[(f >> 7) * 132 + (f & 127)] = W_tag[(f >> 7) * 256 + dir * 128 + (f & 127)];

    float* emdst = emB + (size_t)b * TT * KK;

    for (int tile = 0; tile < TT / 64; tile++) {
        const int tb = tile * 64;
        __syncthreads();
        #pragma unroll
        for (int it = 0; it < 4; it++) {
            const int f4 = it * 512 + j;         // float4 index in tile
            const int tr = f4 >> 5;              // 32 float4 per row
            const int c4 = (f4 & 31) * 4;
            float4 v = *(const float4*)(hdst + (size_t)(tb + tr) * 128 + c4);
            *(float4*)&h_tile[tr * 132 + c4] = v;
        }
        __syncthreads();                 // tile staged
        for (int task = j; task < 64 * KK; task += 512) {
            const int tl = task / 9;
            const int kk = task - tl * 9;
            const float* hp = &h_tile[tl * 132];
            const float* wp = &wt_s[kk * 132];
            float acc = 0.0f;
            #pragma unroll
            for (int i4 = 0; i4 < 32; i4++) {
                float4 h4 = *(const float4*)(hp + i4 * 4);
                float4 w4 = *(const float4*)(wp + i4 * 4);
                acc += h4.x * w4.x + h4.y * w4.y + h4.z * w4.z + h4.w * w4.w;
            }
            if (dir == 1) emdst[(size_t)tb * KK + task] = acc;   // coalesced
            else          em_s[tb * KK + task] = acc;
        }
    }
    __syncthreads();                     // last tile done; emB stores drained

    if (dir == 1) {                      // backward: publish and exit
        if (j == 0) {
            __threadfence();             // agent-scope: emB visible device-wide
            __hip_atomic_fetch_add(&flags[b], 1u, __ATOMIC_RELEASE,
                                   __HIP_MEMORY_SCOPE_AGENT);
        }
        return;
    }

    // forward: wait for the backward partner's half, fold emB + bias
    if (j == 0) {
        while (__hip_atomic_load(&flags[b], __ATOMIC_ACQUIRE,
                                 __HIP_MEMORY_SCOPE_AGENT) == snap)
            __builtin_amdgcn_s_sleep(1);
    }
    __syncthreads();                     // acquire visible to whole block
    for (int f = j; f < TT * KK; f += 512)
        em_s[f] += emdst[f] + b_tag[f % KK];
    __syncthreads();

    // ---- phase V: Viterbi decode on wave 0 (unchanged, proven) ------------
    if (j < 64) {
        const int lane = j;

        float trans_col[KK];
        float score = -1e30f;
        if (lane < KK) {
            #pragma unroll
            for (int i = 0; i < KK; i++) trans_col[i] = trans[i * KK + lane];
            score = start_trans[lane] + em_s[lane];
        }

        float em_cur = (lane < KK) ? em_s[KK + lane] : 0.0f;   // t=1
        for (int t = 1; t < TT; t++) {
            float em_next = (t + 1 < TT && lane < KK) ? em_s[(t + 1) * KK + lane] : 0.0f;

            float my = (lane < KK) ? score : -1e30f;
            float cand[KK];
            #pragma unroll
            for (int i = 0; i < KK; i++) cand[i] = __shfl(my, i) + trans_col[i];

            float v01, v23, v45, v67, v03, v47, v07, vb_;
            int   i01, i23, i45, i67, i03, i47, i07, ib_;
            {
                bool gt;
                gt = cand[1] > cand[0]; v01 = gt ? cand[1] : cand[0]; i01 = gt ? 1 : 0;
                gt = cand[3] > cand[2]; v23 = gt ? cand[3] : cand[2]; i23 = gt ? 3 : 2;
                gt = cand[5] > cand[4]; v45 = gt ? cand[5] : cand[4]; i45 = gt ? 5 : 4;
                gt = cand[7] > cand[6]; v67 = gt ? cand[7] : cand[6]; i67 = gt ? 7 : 6;
                gt = v23 > v01; v03 = gt ? v23 : v01; i03 = gt ? i23 : i01;
                gt = v67 > v45; v47 = gt ? v67 : v45; i47 = gt ? i67 : i45;
                gt = v47 > v03; v07 = gt ? v47 : v03; i07 = gt ? i47 : i03;
                gt = cand[8] > v07; vb_ = gt ? cand[8] : v07; ib_ = gt ? 8 : i07;
            }

            if (lane < KK) {
                bp[t][lane] = (unsigned char)ib_;
                score = vb_ + em_cur;
            }
            em_cur = em_next;
        }

        float fin = (lane < KK) ? (score + end_trans[lane]) : -1e30f;
        float farr[KK];
        #pragma unroll
        for (int jx = 0; jx < KK; jx++) farr[jx] = __shfl(fin, jx);
        float v01, v23, v45, v67, v03, v47, v07, vb_;
        int   i01, i23, i45, i67, i03, i47, i07, bj;
        {
            bool gt;
            gt = farr[1] > farr[0]; v01 = gt ? farr[1] : farr[0]; i01 = gt ? 1 : 0;
            gt = farr[3] > farr[2]; v23 = gt ? farr[3] : farr[2]; i23 = gt ? 3 : 2;
            gt = farr[5] > farr[4]; v45 = gt ? farr[5] : farr[4]; i45 = gt ? 5 : 4;
            gt = farr[7] > farr[6]; v67 = gt ? farr[7] : farr[6]; i67 = gt ? 7 : 6;
            gt = v23 > v01; v03 = gt ? v23 : v01; i03 = gt ? i23 : i01;
            gt = v67 > v45; v47 = gt ? v67 : v45; i47 = gt ? i67 : i45;
            gt = v47 > v03; v07 = gt ? v47 : v03; i07 = gt ? i47 : i03;
            gt = farr[8] > v07; vb_ = gt ? farr[8] : v07; bj = gt ? 8 : i07;
        }

        if (lane == 0) {
            int tag = bj;
            out[b * TT + (TT - 1)] = tag;
            for (int t = TT - 1; t >= 1; t--) {
                tag = bp[t][tag];
                out[b * TT + t - 1] = tag;
            }
        }
    }
}

// ---------------------------------------------------------------------------
extern "C" void kernel_launch(void* const* d_in, const int* in_sizes, int n_in,
                              void* d_out, int out_size, void* d_ws, size_t ws_size,
                              hipStream_t stream)
{
    const int*   x       = (const int*)  d_in[0];
    const float* emb     = (const float*)d_in[1];
    const float* w_ih_f  = (const float*)d_in[2];
    const float* w_hh_f  = (const float*)d_in[3];
    const float* b_ih_f  = (const float*)d_in[4];
    const float* b_hh_f  = (const float*)d_in[5];
    const float* w_ih_b  = (const float*)d_in[6];
    const float* w_hh_b  = (const float*)d_in[7];
    const float* b_ih_b  = (const float*)d_in[8];
    const float* b_hh_b  = (const float*)d_in[9];
    const float* W_tag   = (const float*)d_in[10];
    const float* b_tag   = (const float*)d_in[11];
    const float* start_t = (const float*)d_in[12];
    const float* end_t   = (const float*)d_in[13];
    const float* trans   = (const float*)d_in[14];
    int* out = (int*)d_out;

    const size_t em_elems    = (size_t)BB * TT * KK;       // 2.25 MB
    const size_t state_elems = (size_t)2 * 128 * 128;
    const size_t hall_elems  = (size_t)2 * BB * TT * 128;  // 67 MB, [dir][b][t][k]

    // C=512 preferred: single mega dispatch per bench iteration.
    int C = 32;
    const int cands[5] = {512, 256, 128, 64, 32};
    for (int ci = 0; ci < 5; ci++) {
        size_t need = ((size_t)2 * cands[ci] * BB * 512
                       + em_elems + 2 * state_elems + hall_elems) * sizeof(float)
                      + 16384;
        if (ws_size >= need) { C = cands[ci]; break; }
    }

    float* buf_f   = (float*)d_ws;                        // C*128*512
    float* buf_b   = buf_f + (size_t)C * BB * 512;        // C*128*512
    float* emB     = buf_b + (size_t)C * BB * 512;        // B*T*9
    float* h_state = emB + em_elems;                      // 2*128*128
    float* c_state = h_state + state_elems;               // 2*128*128
    float* h_all   = c_state + state_elems;               // 2*B*T*128
    unsigned* flags  = (unsigned*)(h_all + hall_elems);   // 128 monotonic ctrs
    unsigned* gflags = flags + 128;                       // 2*C producer flags

    const int rounds = TT / C;
    for (int r = 0; r < rounds; r++) {
        const int t0f = r * C;
        const int t0b = TT - (r + 1) * C;
        hipMemsetAsync(gflags, 0, (size_t)2 * C * sizeof(unsigned), stream);
        mega<<<dim3(256 + C * 8), dim3(512), 0, stream>>>(
            x, emb, w_ih_f, w_ih_b, b_ih_f, b_hh_f, b_ih_b, b_hh_b,
            buf_f, buf_b, w_hh_f, w_hh_b, h_all,
            h_state, c_state,
            W_tag, b_tag, start_t, end_t, trans,
            emB, flags, gflags, out,
            t0f, t0b, C, (r == 0) ? 1 : 0, (r == rounds - 1) ? 1 : 0);
    }
}

// Round 11
// 877.495 us; speedup vs baseline: 10.0554x; 10.0554x over previous
//
#include <hip/hip_runtime.h>
#include <math.h>

#define TT 512
#define BB 128
#define KK 9

// ---------------------------------------------------------------------------
// fast activations: v_exp_f32 / v_rcp_f32 based (~1 ulp each)
// ---------------------------------------------------------------------------
__device__ __forceinline__ float fast_sigmoid(float x) {
    const float LOG2E = 1.4426950408889634f;
    float e = __builtin_amdgcn_exp2f(-x * LOG2E);
    return __builtin_amdgcn_rcpf(1.0f + e);
}
__device__ __forceinline__ float fast_tanh(float x) {
    const float LOG2E = 1.4426950408889634f;
    float a = fabsf(x);
    float e = __builtin_amdgcn_exp2f(-2.0f * a * LOG2E);   // in (0,1]
    float t = (1.0f - e) * __builtin_amdgcn_rcpf(1.0f + e);
    return copysignf(t, x);
}

// ---------------------------------------------------------------------------
// G: input projection — VERBATIM R5 (best measured, 847us wall).
// 1 timestep/block, (256,3), bank-fixed B-fragment split tx*4 / 64+tx*4.
// R8/R10 lessons: never cap occupancy past the VGPR budget (spill
// catastrophe); G is stall-bound ~375us, insensitive to LDS-instr count
// (R15), TLP (R4), conflicts (R14) — accepted as floor for this structure.
// ---------------------------------------------------------------------------
__global__ __launch_bounds__(256, 3) void input_gemm(
    const int* __restrict__ x, const float* __restrict__ emb,
    const float* __restrict__ w_ih_f, const float* __restrict__ w_ih_b,
    const float* __restrict__ b_ih_f, const float* __restrict__ b_hh_f,
    const float* __restrict__ b_ih_b, const float* __restrict__ b_hh_b,
    float* __restrict__ buf_f, float* __restrict__ buf_b,
    int t0f, int t0b)
{
    const int dir = blockIdx.z;
    const int s   = blockIdx.x;           // local timestep within chunk
    const int n0  = blockIdx.y * 128;     // gate tile base
    const int t   = (dir ? t0b : t0f) + s;
    const float* w  = dir ? w_ih_b : w_ih_f;
    const float* bi = dir ? b_ih_b : b_ih_f;
    const float* bh = dir ? b_hh_b : b_hh_f;
    float* dst = dir ? buf_b : buf_f;

    __shared__ __align__(16) float As[32][132];   // [k][row] 16.9 KB
    __shared__ __align__(16) float Bs[32][132];   // [k][gate] 16.9 KB

    const int tid  = threadIdx.x;
    const int lrow = tid >> 3;            // 0..31
    const int k4   = (tid & 7) * 4;       // 0..28

    int tokr[4];
    #pragma unroll
    for (int p = 0; p < 4; p++) tokr[p] = x[(p * 32 + lrow) * TT + t];

    const int tx = tid & 15;
    const int ty = tid >> 4;

    float acc[8][8];
    #pragma unroll
    for (int i = 0; i < 8; i++)
        #pragma unroll
        for (int j = 0; j < 8; j++) acc[i][j] = 0.0f;

    float4 aS[4], bS[4];
    #pragma unroll
    for (int p = 0; p < 4; p++) {
        aS[p] = *(const float4*)(emb + (size_t)tokr[p] * 128 + k4);
        bS[p] = *(const float4*)(w + (size_t)(n0 + p * 32 + lrow) * 128 + k4);
    }

    for (int kc = 0; kc < 128; kc += 32) {
        __syncthreads();                 // prev chunk's reads done
        #pragma unroll
        for (int p = 0; p < 4; p++) {
            const int row = p * 32 + lrow;
            As[k4 + 0][row] = aS[p].x; As[k4 + 1][row] = aS[p].y;
            As[k4 + 2][row] = aS[p].z; As[k4 + 3][row] = aS[p].w;
            Bs[k4 + 0][row] = bS[p].x; Bs[k4 + 1][row] = bS[p].y;
            Bs[k4 + 2][row] = bS[p].z; Bs[k4 + 3][row] = bS[p].w;
        }
        __syncthreads();                 // staging visible
        if (kc + 32 < 128) {             // prefetch next chunk (hidden by compute)
            #pragma unroll
            for (int p = 0; p < 4; p++) {
                aS[p] = *(const float4*)(emb + (size_t)tokr[p] * 128 + kc + 32 + k4);
                bS[p] = *(const float4*)(w + (size_t)(n0 + p * 32 + lrow) * 128 + kc + 32 + k4);
            }
        }
        #pragma unroll 8
        for (int k = 0; k < 32; k++) {
            float4 af0 = *(const float4*)&As[k][ty * 8];
            float4 af1 = *(const float4*)&As[k][ty * 8 + 4];
            float4 bf0 = *(const float4*)&Bs[k][tx * 4];        // banks: 2-way, free
            float4 bf1 = *(const float4*)&Bs[k][64 + tx * 4];   // banks: 2-way, free
            float a_[8] = {af0.x, af0.y, af0.z, af0.w, af1.x, af1.y, af1.z, af1.w};
            float b_[8] = {bf0.x, bf0.y, bf0.z, bf0.w, bf1.x, bf1.y, bf1.z, bf1.w};
            #pragma unroll
            for (int i = 0; i < 8; i++)
                #pragma unroll
                for (int j = 0; j < 8; j++)
                    acc[i][j] += a_[i] * b_[j];
        }
    }

    // thread owns gate columns nb0+0..3 (acc[][0..3]) and nb1+0..3 (acc[][4..7])
    const int nb0 = n0 + tx * 4;
    const int nb1 = n0 + 64 + tx * 4;
    float bias[8];
    #pragma unroll
    for (int j = 0; j < 4; j++) {
        bias[j]     = bi[nb0 + j] + bh[nb0 + j];
        bias[4 + j] = bi[nb1 + j] + bh[nb1 + j];
    }
    #pragma unroll
    for (int i = 0; i < 8; i++) {
        int brow = ty * 8 + i;
        float* o = dst + ((size_t)s * 128 + brow) * 512;
        float4 v0, v1;
        v0.x = acc[i][0] + bias[0]; v0.y = acc[i][1] + bias[1];
        v0.z = acc[i][2] + bias[2]; v0.w = acc[i][3] + bias[3];
        v1.x = acc[i][4] + bias[4]; v1.y = acc[i][5] + bias[5];
        v1.z = acc[i][6] + bias[6]; v1.w = acc[i][7] + bias[7];
        *(float4*)(o + nb0) = v0;
        *(float4*)(o + nb1) = v1;
    }
}

// ---------------------------------------------------------------------------
// L: LSTM recurrence (R0-exact barrier region) + tail phase C emissions +
// fused Viterbi. R5-verbatim EXCEPT the backtrack: the 511-step serial
// dependent-LDS chase (~25us on 1 lane) is replaced by parallel suffix
// composition of the 9-entry backpointer maps (pointer doubling, 9
// rounds, all 512 threads). Integer-exact: out[t-1] =
// bp[t]o...obp[511](bj) computed by function composition — identical
// values, no FP involved. Maps double-buffered in h_tile (free after
// phase C; 9.2KB of 33.8KB).
// ---------------------------------------------------------------------------
__global__ __launch_bounds__(512, 2) void lstm_fused(
    const float* __restrict__ buf_f, const float* __restrict__ buf_b,
    const float* __restrict__ w_hh_f, const float* __restrict__ w_hh_b,
    float* __restrict__ h_all,
    float* __restrict__ h_state, float* __restrict__ c_state,
    const float* __restrict__ W_tag, const float* __restrict__ b_tag,
    const float* __restrict__ start_trans, const float* __restrict__ end_trans,
    const float* __restrict__ trans,
    float* __restrict__ emB, unsigned* __restrict__ flags,
    int* __restrict__ out,
    int t0f, int t0b, int C, int init, int tail)
{
    const int dir = blockIdx.x >> 7;
    const int b   = blockIdx.x & 127;
    const int j   = threadIdx.x;
    const int w_  = j >> 6;          // wave id 0..7
    const int l   = j & 63;
    const int m   = l >> 2;          // group 0..15
    const int q   = l & 3;           // gate: 0=i 1=f 2=g 3=o
    const int k   = w_ * 16 + m;     // h index 0..127
    const int r   = q * 128 + k;     // gate row in [0,512)

    unsigned snap = 0u;
    if (tail && dir == 0 && j == 0)
        snap = __hip_atomic_load(&flags[b], __ATOMIC_RELAXED, __HIP_MEMORY_SCOPE_AGENT);

    const float* whh = dir ? w_hh_b : w_hh_f;
    float wR[128];
    #pragma unroll
    for (int qq = 0; qq < 32; qq++) {
        float4 v = *(const float4*)(whh + (size_t)r * 128 + qq * 4);
        wR[4*qq+0] = v.x; wR[4*qq+1] = v.y; wR[4*qq+2] = v.z; wR[4*qq+3] = v.w;
    }

    __shared__ __align__(16) float h_lds[2][128];    // 1 KB
    __shared__ __align__(16) float wt_s[KK * 132];   // 4.6 KB (padded)
    __shared__ __align__(16) float em_s[TT * KK];    // 18.4 KB
    __shared__ __align__(16) float h_tile[64 * 132]; // 33.8 KB (padded; reused
                                                     // for backtrack maps)
    __shared__ unsigned char bp[TT][KK];             // 4.6 KB
    __shared__ int bj_s;

    float c;
    if (init) {
        c = 0.0f;
        if (q == 0) h_lds[0][k] = 0.0f;
    } else {
        c = c_state[((size_t)dir * 128 + b) * 128 + k];
        if (q == 0) h_lds[0][k] = h_state[((size_t)dir * 128 + b) * 128 + k];
    }
    __syncthreads();                     // h_lds[0] visible

    const float* buf = dir ? buf_b : buf_f;
    const int t0     = dir ? t0b : t0f;
    const int  tl0   = dir ? (C - 1) : 0;
    const long lstep = dir ? -(long)(128 * 512) : (long)(128 * 512);

    const float* xp = buf + ((size_t)tl0 * 128 + b) * 512 + r;
    float xw = *xp;
    float h_reg = 0.0f;

    float* hdst = h_all + (size_t)(dir * BB + b) * TT * 128;   // private region

    for (int s = 0; s < C; s++) {
        const int t = t0 + (dir ? (C - 1 - s) : s);
        const int p = s & 1;
        const float* hprev = h_lds[p];

        float a0 = 0.f, a1 = 0.f, a2 = 0.f, a3 = 0.f;
        #pragma unroll
        for (int qq = 0; qq < 32; qq++) {
            float4 h4 = *(const float4*)&hprev[4 * qq];
            a0 += wR[4*qq+0] * h4.x;
            a1 += wR[4*qq+1] * h4.y;
            a2 += wR[4*qq+2] * h4.z;
            a3 += wR[4*qq+3] * h4.w;
        }
        float pre = xw + ((a0 + a1) + (a2 + a3));

        float act = (q == 2) ? fast_tanh(pre) : fast_sigmoid(pre);

        float f_ = __shfl_xor(act, 1);   // q0 <- q1 (f)
        float g_ = __shfl_xor(act, 2);   // q0 <- q2 (g)
        float o_ = __shfl_xor(act, 3);   // q0 <- q3 (o)

        c = f_ * c + act * g_;           // act == i on q0
        h_reg = o_ * fast_tanh(c);
        if (q == 0) h_lds[p ^ 1][k] = h_reg;

        __syncthreads();                 // h_t visible to all waves

        // post-barrier: issue global ops with a full step of slack
        if (s + 1 < C) { xp += lstep; xw = *xp; }
        if (q == 0)
            hdst[(size_t)t * 128 + k] = h_reg;
    }

    if (q == 0) {
        h_state[((size_t)dir * 128 + b) * 128 + k] = h_reg;
        c_state[((size_t)dir * 128 + b) * 128 + k] = c;
    }

    if (!tail) return;                   // chunked path: only last round decodes

    // ---- phase C: staged, coalesced emission GEMM -------------------------
    for (int f = j; f < KK * 128; f += 512)
        wt_s[(f >> 7) * 132 + (f & 127)] = W_tag[(f >> 7) * 256 + dir * 128 + (f & 127)];

    float* emdst = emB + (size_t)b * TT * KK;

    for (int tile = 0; tile < TT / 64; tile++) {
        const int tb = tile * 64;
        __syncthreads();
        #pragma unroll
        for (int it = 0; it < 4; it++) {
            const int f4 = it * 512 + j;         // float4 index in tile
            const int tr = f4 >> 5;              // 32 float4 per row
            const int c4 = (f4 & 31) * 4;
            float4 v = *(const float4*)(hdst + (size_t)(tb + tr) * 128 + c4);
            *(float4*)&h_tile[tr * 132 + c4] = v;
        }
        __syncthreads();                 // tile staged
        for (int task = j; task < 64 * KK; task += 512) {
            const int tl = task / 9;
            const int kk = task - tl * 9;
            const float* hp = &h_tile[tl * 132];
            const float* wp = &wt_s[kk * 132];
            float acc = 0.0f;
            #pragma unroll
            for (int i4 = 0; i4 < 32; i4++) {
                float4 h4 = *(const float4*)(hp + i4 * 4);
                float4 w4 = *(const float4*)(wp + i4 * 4);
                acc += h4.x * w4.x + h4.y * w4.y + h4.z * w4.z + h4.w * w4.w;
            }
            if (dir == 1) emdst[(size_t)tb * KK + task] = acc;   // coalesced
            else          em_s[tb * KK + task] = acc;
        }
    }
    __syncthreads();                     // last tile done; emB stores drained

    if (dir == 1) {                      // backward: publish and exit
        if (j == 0) {
            __threadfence();             // agent-scope: emB visible device-wide
            __hip_atomic_fetch_add(&flags[b], 1u, __ATOMIC_RELEASE,
                                   __HIP_MEMORY_SCOPE_AGENT);
        }
        return;
    }

    // forward: wait for the backward partner's half, fold emB + bias
    if (j == 0) {
        while (__hip_atomic_load(&flags[b], __ATOMIC_ACQUIRE,
                                 __HIP_MEMORY_SCOPE_AGENT) == snap)
            __builtin_amdgcn_s_sleep(1);
    }
    __syncthreads();                     // acquire visible to whole block
    for (int f = j; f < TT * KK; f += 512)
        em_s[f] += emdst[f] + b_tag[f % KK];
    __syncthreads();

    // ---- phase V: Viterbi forward pass on wave 0 (unchanged, proven) ------
    if (j < 64) {
        const int lane = j;

        float trans_col[KK];
        float score = -1e30f;
        if (lane < KK) {
            #pragma unroll
            for (int i = 0; i < KK; i++) trans_col[i] = trans[i * KK + lane];
            score = start_trans[lane] + em_s[lane];
        }

        float em_cur = (lane < KK) ? em_s[KK + lane] : 0.0f;   // t=1
        for (int t = 1; t < TT; t++) {
            float em_next = (t + 1 < TT && lane < KK) ? em_s[(t + 1) * KK + lane] : 0.0f;

            float my = (lane < KK) ? score : -1e30f;
            float cand[KK];
            #pragma unroll
            for (int i = 0; i < KK; i++) cand[i] = __shfl(my, i) + trans_col[i];

            float v01, v23, v45, v67, v03, v47, v07, vb_;
            int   i01, i23, i45, i67, i03, i47, i07, ib_;
            {
                bool gt;
                gt = cand[1] > cand[0]; v01 = gt ? cand[1] : cand[0]; i01 = gt ? 1 : 0;
                gt = cand[3] > cand[2]; v23 = gt ? cand[3] : cand[2]; i23 = gt ? 3 : 2;
                gt = cand[5] > cand[4]; v45 = gt ? cand[5] : cand[4]; i45 = gt ? 5 : 4;
                gt = cand[7] > cand[6]; v67 = gt ? cand[7] : cand[6]; i67 = gt ? 7 : 6;
                gt = v23 > v01; v03 = gt ? v23 : v01; i03 = gt ? i23 : i01;
                gt = v67 > v45; v47 = gt ? v67 : v45; i47 = gt ? i67 : i45;
                gt = v47 > v03; v07 = gt ? v47 : v03; i07 = gt ? i47 : i03;
                gt = cand[8] > v07; vb_ = gt ? cand[8] : v07; ib_ = gt ? 8 : i07;
            }

            if (lane < KK) {
                bp[t][lane] = (unsigned char)ib_;
                score = vb_ + em_cur;
            }
            em_cur = em_next;
        }

        float fin = (lane < KK) ? (score + end_trans[lane]) : -1e30f;
        float farr[KK];
        #pragma unroll
        for (int jx = 0; jx < KK; jx++) farr[jx] = __shfl(fin, jx);
        float v01, v23, v45, v67, v03, v47, v07, vb_;
        int   i01, i23, i45, i67, i03, i47, i07, bj;
        {
            bool gt;
            gt = farr[1] > farr[0]; v01 = gt ? farr[1] : farr[0]; i01 = gt ? 1 : 0;
            gt = farr[3] > farr[2]; v23 = gt ? farr[3] : farr[2]; i23 = gt ? 3 : 2;
            gt = farr[5] > farr[4]; v45 = gt ? farr[5] : farr[4]; i45 = gt ? 5 : 4;
            gt = farr[7] > farr[6]; v67 = gt ? farr[7] : farr[6]; i67 = gt ? 7 : 6;
            gt = v23 > v01; v03 = gt ? v23 : v01; i03 = gt ? i23 : i01;
            gt = v67 > v45; v47 = gt ? v67 : v45; i47 = gt ? i67 : i45;
            gt = v47 > v03; v07 = gt ? v47 : v03; i07 = gt ? i47 : i03;
            gt = farr[8] > v07; vb_ = gt ? farr[8] : v07; bj = gt ? 8 : i07;
        }

        if (lane == 0) {
            bj_s = bj;
            out[b * TT + (TT - 1)] = bj;
        }
    }
    __syncthreads();                     // bp[][] + bj_s visible to all threads

    // ---- parallel backtrack: suffix-compose bp maps (pointer doubling) ----
    // out[t-1] = bp[t] o bp[t+1] o ... o bp[TT-1] (bj).  Each map is 9
    // bytes; compose in log2(TT)=9 rounds. Thread j owns map t=j.
    {
        unsigned char* mA = (unsigned char*)h_tile;          // [TT][KK]
        unsigned char* mB = mA + TT * KK;
        #pragma unroll
        for (int i = 0; i < KK; i++)
            mA[j * KK + i] = (j >= 1) ? bp[j][i] : (unsigned char)0;
        __syncthreads();
        for (int kk = 1; kk < TT; kk <<= 1) {
            if (j >= 1) {
                if (j + kk < TT) {
                    #pragma unroll
                    for (int i = 0; i < KK; i++)
                        mB[j * KK + i] = mA[j * KK + mA[(j + kk) * KK + i]];
                } else {
                    #pragma unroll
                    for (int i = 0; i < KK; i++)
                        mB[j * KK + i] = mA[j * KK + i];
                }
            }
            __syncthreads();
            unsigned char* tmp = mA; mA = mB; mB = tmp;
        }
        if (j >= 1)
            out[b * TT + (j - 1)] = mA[j * KK + bj_s];
    }
}

// ---------------------------------------------------------------------------
extern "C" void kernel_launch(void* const* d_in, const int* in_sizes, int n_in,
                              void* d_out, int out_size, void* d_ws, size_t ws_size,
                              hipStream_t stream)
{
    const int*   x       = (const int*)  d_in[0];
    const float* emb     = (const float*)d_in[1];
    const float* w_ih_f  = (const float*)d_in[2];
    const float* w_hh_f  = (const float*)d_in[3];
    const float* b_ih_f  = (const float*)d_in[4];
    const float* b_hh_f  = (const float*)d_in[5];
    const float* w_ih_b  = (const float*)d_in[6];
    const float* w_hh_b  = (const float*)d_in[7];
    const float* b_ih_b  = (const float*)d_in[8];
    const float* b_hh_b  = (const float*)d_in[9];
    const float* W_tag   = (const float*)d_in[10];
    const float* b_tag   = (const float*)d_in[11];
    const float* start_t = (const float*)d_in[12];
    const float* end_t   = (const float*)d_in[13];
    const float* trans   = (const float*)d_in[14];
    int* out = (int*)d_out;

    const size_t em_elems    = (size_t)BB * TT * KK;       // 2.25 MB
    const size_t state_elems = (size_t)2 * 128 * 128;
    const size_t hall_elems  = (size_t)2 * BB * TT * 128;  // 67 MB, [dir][b][t][k]

    // C=512 preferred: single lstm dispatch (fixed dispatch cost ~52us).
    int C = 32;
    const int cands[5] = {512, 256, 128, 64, 32};
    for (int ci = 0; ci < 5; ci++) {
        size_t need = ((size_t)2 * cands[ci] * BB * 512
                       + em_elems + 2 * state_elems + hall_elems) * sizeof(float)
                      + 1024;
        if (ws_size >= need) { C = cands[ci]; break; }
    }

    float* buf_f   = (float*)d_ws;                        // C*128*512
    float* buf_b   = buf_f + (size_t)C * BB * 512;        // C*128*512
    float* emB     = buf_b + (size_t)C * BB * 512;        // B*T*9
    float* h_state = emB + em_elems;                      // 2*128*128
    float* c_state = h_state + state_elems;               // 2*128*128
    float* h_all   = c_state + state_elems;               // 2*B*T*128
    unsigned* flags = (unsigned*)(h_all + hall_elems);    // 128 monotonic ctrs

    const int rounds = TT / C;
    for (int r = 0; r < rounds; r++) {
        const int t0f = r * C;
        const int t0b = TT - (r + 1) * C;
        dim3 gg(C, 4, 2);
        input_gemm<<<gg, dim3(256), 0, stream>>>(
            x, emb, w_ih_f, w_ih_b, b_ih_f, b_hh_f, b_ih_b, b_hh_b,
            buf_f, buf_b, t0f, t0b);
        lstm_fused<<<dim3(256), dim3(512), 0, stream>>>(
            buf_f, buf_b, w_hh_f, w_hh_b, h_all,
            h_state, c_state,
            W_tag, b_tag, start_t, end_t, trans,
            emB, flags, out,
            t0f, t0b, C, (r == 0) ? 1 : 0, (r == rounds - 1) ? 1 : 0);
    }
}

// Round 12
// 850.402 us; speedup vs baseline: 10.3758x; 1.0319x over previous
//
#include <hip/hip_runtime.h>
#include <math.h>

#define TT 512
#define BB 128
#define KK 9

// ---------------------------------------------------------------------------
// fast activations: v_exp_f32 / v_rcp_f32 based (~1 ulp each)
// ---------------------------------------------------------------------------
__device__ __forceinline__ float fast_sigmoid(float x) {
    const float LOG2E = 1.4426950408889634f;
    float e = __builtin_amdgcn_exp2f(-x * LOG2E);
    return __builtin_amdgcn_rcpf(1.0f + e);
}
__device__ __forceinline__ float fast_tanh(float x) {
    const float LOG2E = 1.4426950408889634f;
    float a = fabsf(x);
    float e = __builtin_amdgcn_exp2f(-2.0f * a * LOG2E);   // in (0,1]
    float t = (1.0f - e) * __builtin_amdgcn_rcpf(1.0f + e);
    return copysignf(t, x);
}

// ---------------------------------------------------------------------------
// FUSED (R19): input projection absorbed into the L block as PHASE A.
// Rationale: standalone G ran its 8.6 GMAC in 375us across 4096 short
// blocks (stall/churn-bound: insensitive to LDS instrs (R15), TLP (R4),
// conflicts (R14); spills when bounded (R8)). Per (dir,b) block the
// needed projections are a PRIVATE 512x512x128 GEMM (33.5M MAC = 109us
// at full VALU rate on one CU) with zero inter-block dependency -> run
// it as a prologue inside each L block. One dispatch per iteration; no
// flags/memset/spin (R9/R10 lesson: no cross-role scheduling at all).
// Phase A: 8x8-per-thread register tiles (G's proven math, same k
// summation order -> bit-identical); LDS tiles aliased on tail arrays
// (As2->em_s 16.9K, Bs2->h_tile 33.3K, x_s->wt_s 2K). A-frag reads are
// 2-addr broadcast; B-frags split at +128 (R14 bank fix).
// Phase B: recurrence + tail VERBATIM R11 (incl. parallel backtrack).
// ---------------------------------------------------------------------------
__global__ __launch_bounds__(512, 2) void lstm_fused(
    const int* __restrict__ x, const float* __restrict__ emb,
    const float* __restrict__ w_ih_f, const float* __restrict__ w_ih_b,
    const float* __restrict__ b_ih_f, const float* __restrict__ b_hh_f,
    const float* __restrict__ b_ih_b, const float* __restrict__ b_hh_b,
    float* __restrict__ buf2,
    const float* __restrict__ w_hh_f, const float* __restrict__ w_hh_b,
    float* __restrict__ h_all,
    float* __restrict__ h_state, float* __restrict__ c_state,
    const float* __restrict__ W_tag, const float* __restrict__ b_tag,
    const float* __restrict__ start_trans, const float* __restrict__ end_trans,
    const float* __restrict__ trans,
    float* __restrict__ emB, unsigned* __restrict__ flags,
    int* __restrict__ out,
    int t0f, int t0b, int C, int init, int tail)
{
    const int dir = blockIdx.x >> 7;
    const int b   = blockIdx.x & 127;
    const int j   = threadIdx.x;

    __shared__ __align__(16) float h_lds[2][128];    // 1 KB
    __shared__ __align__(16) float wt_s[KK * 132];   // 4.6 KB (A: x_s)
    __shared__ __align__(16) float em_s[TT * KK];    // 18.4 KB (A: As2)
    __shared__ __align__(16) float h_tile[64 * 132]; // 33.8 KB (A: Bs2)
    __shared__ unsigned char bp[TT][KK];             // 4.6 KB
    __shared__ int bj_s;

    unsigned snap = 0u;
    if (tail && dir == 0 && j == 0)
        snap = __hip_atomic_load(&flags[b], __ATOMIC_RELAXED, __HIP_MEMORY_SCOPE_AGENT);

    const int t0 = dir ? t0b : t0f;

    // ==================== PHASE A: private input GEMM ======================
    {
        int*   x_s = (int*)wt_s;         // C tokens (<= 2 KB)
        float* As2 = em_s;               // [32][132] emb tile (t-rows)
        float* Bs2 = h_tile;             // [32][260] w_ih tile (gate rows)
        const float* wih = dir ? w_ih_b : w_ih_f;
        const float* bi  = dir ? b_ih_b : b_ih_f;
        const float* bh  = dir ? b_hh_b : b_hh_f;
        float* myb = buf2 + (size_t)(dir * BB + b) * C * 512;

        for (int f = j; f < C; f += 512) x_s[f] = x[b * TT + t0 + f];
        __syncthreads();

        const int ty  = j >> 5;          // 0..15  (t sub-row group)
        const int tx  = j & 31;          // 0..31  (gate columns)
        const int Atr = j >> 2;          // 0..127 A-stage row
        const int Aq  = (j & 3) * 8;     // A-stage k base {0,8,16,24}
        const int Bgr = j >> 1;          // 0..255 B-stage row
        const int Bq  = (j & 1) * 16;    // B-stage k base {0,16}

        const int ntg = C >> 7;          // C/128 t-groups
        for (int gg = 0; gg < 2; gg++) {
            const int g0 = gg * 256 + tx * 4;
            const int g1 = g0 + 128;
            float bias0[4], bias1[4];
            #pragma unroll
            for (int u = 0; u < 4; u++) {
                bias0[u] = bi[g0 + u] + bh[g0 + u];
                bias1[u] = bi[g1 + u] + bh[g1 + u];
            }
            const float* bBase = wih + (size_t)(gg * 256 + Bgr) * 128;

            for (int tg = 0; tg < ntg; tg++) {
                float acc[8][8];
                #pragma unroll
                for (int i = 0; i < 8; i++)
                    #pragma unroll
                    for (int jj = 0; jj < 8; jj++) acc[i][jj] = 0.0f;

                const int tokA = x_s[tg * 128 + Atr];
                const float* aBase = emb + (size_t)tokA * 128;

                float4 aP0 = *(const float4*)(aBase + Aq);
                float4 aP1 = *(const float4*)(aBase + Aq + 4);
                float4 bP0 = *(const float4*)(bBase + Bq);
                float4 bP1 = *(const float4*)(bBase + Bq + 4);
                float4 bP2 = *(const float4*)(bBase + Bq + 8);
                float4 bP3 = *(const float4*)(bBase + Bq + 12);

                for (int kc = 0; kc < 128; kc += 32) {
                    __syncthreads();             // prev chunk's reads done
                    As2[(Aq + 0) * 132 + Atr] = aP0.x;
                    As2[(Aq + 1) * 132 + Atr] = aP0.y;
                    As2[(Aq + 2) * 132 + Atr] = aP0.z;
                    As2[(Aq + 3) * 132 + Atr] = aP0.w;
                    As2[(Aq + 4) * 132 + Atr] = aP1.x;
                    As2[(Aq + 5) * 132 + Atr] = aP1.y;
                    As2[(Aq + 6) * 132 + Atr] = aP1.z;
                    As2[(Aq + 7) * 132 + Atr] = aP1.w;
                    Bs2[(Bq + 0) * 260 + Bgr] = bP0.x;
                    Bs2[(Bq + 1) * 260 + Bgr] = bP0.y;
                    Bs2[(Bq + 2) * 260 + Bgr] = bP0.z;
                    Bs2[(Bq + 3) * 260 + Bgr] = bP0.w;
                    Bs2[(Bq + 4) * 260 + Bgr] = bP1.x;
                    Bs2[(Bq + 5) * 260 + Bgr] = bP1.y;
                    Bs2[(Bq + 6) * 260 + Bgr] = bP1.z;
                    Bs2[(Bq + 7) * 260 + Bgr] = bP1.w;
                    Bs2[(Bq + 8) * 260 + Bgr] = bP2.x;
                    Bs2[(Bq + 9) * 260 + Bgr] = bP2.y;
                    Bs2[(Bq + 10) * 260 + Bgr] = bP2.z;
                    Bs2[(Bq + 11) * 260 + Bgr] = bP2.w;
                    Bs2[(Bq + 12) * 260 + Bgr] = bP3.x;
                    Bs2[(Bq + 13) * 260 + Bgr] = bP3.y;
                    Bs2[(Bq + 14) * 260 + Bgr] = bP3.z;
                    Bs2[(Bq + 15) * 260 + Bgr] = bP3.w;
                    __syncthreads();             // staging visible
                    if (kc + 32 < 128) {         // prefetch next chunk
                        aP0 = *(const float4*)(aBase + kc + 32 + Aq);
                        aP1 = *(const float4*)(aBase + kc + 32 + Aq + 4);
                        bP0 = *(const float4*)(bBase + kc + 32 + Bq);
                        bP1 = *(const float4*)(bBase + kc + 32 + Bq + 4);
                        bP2 = *(const float4*)(bBase + kc + 32 + Bq + 8);
                        bP3 = *(const float4*)(bBase + kc + 32 + Bq + 12);
                    }
                    #pragma unroll 8
                    for (int k = 0; k < 32; k++) {
                        float4 af0 = *(const float4*)&As2[k * 132 + ty * 8];
                        float4 af1 = *(const float4*)&As2[k * 132 + ty * 8 + 4];
                        float4 bf0 = *(const float4*)&Bs2[k * 260 + tx * 4];
                        float4 bf1 = *(const float4*)&Bs2[k * 260 + 128 + tx * 4];
                        float a_[8] = {af0.x, af0.y, af0.z, af0.w,
                                       af1.x, af1.y, af1.z, af1.w};
                        float b_[8] = {bf0.x, bf0.y, bf0.z, bf0.w,
                                       bf1.x, bf1.y, bf1.z, bf1.w};
                        #pragma unroll
                        for (int i = 0; i < 8; i++)
                            #pragma unroll
                            for (int jj = 0; jj < 8; jj++)
                                acc[i][jj] += a_[i] * b_[jj];
                    }
                }
                // store this (t-group, gate-group) with bias
                #pragma unroll
                for (int i = 0; i < 8; i++) {
                    const int tl = tg * 128 + ty * 8 + i;
                    float* o = myb + (size_t)tl * 512;
                    float4 v0, v1;
                    v0.x = acc[i][0] + bias0[0]; v0.y = acc[i][1] + bias0[1];
                    v0.z = acc[i][2] + bias0[2]; v0.w = acc[i][3] + bias0[3];
                    v1.x = acc[i][4] + bias1[0]; v1.y = acc[i][5] + bias1[1];
                    v1.z = acc[i][6] + bias1[2]; v1.w = acc[i][7] + bias1[3];
                    *(float4*)(o + g0) = v0;
                    *(float4*)(o + g1) = v1;
                }
            }
        }
    }

    // ==================== PHASE B: recurrence (proven R11) =================
    const int w_  = j >> 6;          // wave id 0..7
    const int l   = j & 63;
    const int m   = l >> 2;          // group 0..15
    const int q   = l & 3;           // gate: 0=i 1=f 2=g 3=o
    const int k   = w_ * 16 + m;     // h index 0..127
    const int r   = q * 128 + k;     // gate row in [0,512)

    const float* whh = dir ? w_hh_b : w_hh_f;
    float wR[128];
    #pragma unroll
    for (int qq = 0; qq < 32; qq++) {
        float4 v = *(const float4*)(whh + (size_t)r * 128 + qq * 4);
        wR[4*qq+0] = v.x; wR[4*qq+1] = v.y; wR[4*qq+2] = v.z; wR[4*qq+3] = v.w;
    }

    float c;
    if (init) {
        c = 0.0f;
        if (q == 0) h_lds[0][k] = 0.0f;
    } else {
        c = c_state[((size_t)dir * 128 + b) * 128 + k];
        if (q == 0) h_lds[0][k] = h_state[((size_t)dir * 128 + b) * 128 + k];
    }
    __syncthreads();       // h_lds[0] visible + phase A buf2 stores drained

    const int  tl0   = dir ? (C - 1) : 0;
    const long lstep = dir ? -(long)512 : (long)512;

    const float* xp = buf2 + ((size_t)(dir * BB + b) * C + tl0) * 512 + r;
    float xw = *xp;
    float h_reg = 0.0f;

    float* hdst = h_all + (size_t)(dir * BB + b) * TT * 128;   // private region

    for (int s = 0; s < C; s++) {
        const int t = t0 + (dir ? (C - 1 - s) : s);
        const int p = s & 1;
        const float* hprev = h_lds[p];

        float a0 = 0.f, a1 = 0.f, a2 = 0.f, a3 = 0.f;
        #pragma unroll
        for (int qq = 0; qq < 32; qq++) {
            float4 h4 = *(const float4*)&hprev[4 * qq];
            a0 += wR[4*qq+0] * h4.x;
            a1 += wR[4*qq+1] * h4.y;
            a2 += wR[4*qq+2] * h4.z;
            a3 += wR[4*qq+3] * h4.w;
        }
        float pre = xw + ((a0 + a1) + (a2 + a3));

        float act = (q == 2) ? fast_tanh(pre) : fast_sigmoid(pre);

        float f_ = __shfl_xor(act, 1);   // q0 <- q1 (f)
        float g_ = __shfl_xor(act, 2);   // q0 <- q2 (g)
        float o_ = __shfl_xor(act, 3);   // q0 <- q3 (o)

        c = f_ * c + act * g_;           // act == i on q0
        h_reg = o_ * fast_tanh(c);
        if (q == 0) h_lds[p ^ 1][k] = h_reg;

        __syncthreads();                 // h_t visible to all waves

        // post-barrier: issue global ops with a full step of slack
        if (s + 1 < C) { xp += lstep; xw = *xp; }
        if (q == 0)
            hdst[(size_t)t * 128 + k] = h_reg;
    }

    if (q == 0) {
        h_state[((size_t)dir * 128 + b) * 128 + k] = h_reg;
        c_state[((size_t)dir * 128 + b) * 128 + k] = c;
    }

    if (!tail) return;                   // chunked path: only last round decodes

    // ---- phase C: staged, coalesced emission GEMM -------------------------
    for (int f = j; f < KK * 128; f += 512)
        wt_s[(f >> 7) * 132 + (f & 127)] = W_tag[(f >> 7) * 256 + dir * 128 + (f & 127)];

    float* emdst = emB + (size_t)b * TT * KK;

    for (int tile = 0; tile < TT / 64; tile++) {
        const int tb = tile * 64;
        __syncthreads();
        #pragma unroll
        for (int it = 0; it < 4; it++) {
            const int f4 = it * 512 + j;         // float4 index in tile
            const int tr = f4 >> 5;              // 32 float4 per row
            const int c4 = (f4 & 31) * 4;
            float4 v = *(const float4*)(hdst + (size_t)(tb + tr) * 128 + c4);
            *(float4*)&h_tile[tr * 132 + c4] = v;
        }
        __syncthreads();                 // tile staged
        for (int task = j; task < 64 * KK; task += 512) {
            const int tl = task / 9;
            const int kk = task - tl * 9;
            const float* hp = &h_tile[tl * 132];
            const float* wp = &wt_s[kk * 132];
            float acc = 0.0f;
            #pragma unroll
            for (int i4 = 0; i4 < 32; i4++) {
                float4 h4 = *(const float4*)(hp + i4 * 4);
                float4 w4 = *(const float4*)(wp + i4 * 4);
                acc += h4.x * w4.x + h4.y * w4.y + h4.z * w4.z + h4.w * w4.w;
            }
            if (dir == 1) emdst[(size_t)tb * KK + task] = acc;   // coalesced
            else          em_s[tb * KK + task] = acc;
        }
    }
    __syncthreads();                     // last tile done; emB stores drained

    if (dir == 1) {                      // backward: publish and exit
        if (j == 0) {
            __threadfence();             // agent-scope: emB visible device-wide
            __hip_atomic_fetch_add(&flags[b], 1u, __ATOMIC_RELEASE,
                                   __HIP_MEMORY_SCOPE_AGENT);
        }
        return;
    }

    // forward: wait for the backward partner's half, fold emB + bias
    if (j == 0) {
        while (__hip_atomic_load(&flags[b], __ATOMIC_ACQUIRE,
                                 __HIP_MEMORY_SCOPE_AGENT) == snap)
            __builtin_amdgcn_s_sleep(1);
    }
    __syncthreads();                     // acquire visible to whole block
    for (int f = j; f < TT * KK; f += 512)
        em_s[f] += emdst[f] + b_tag[f % KK];
    __syncthreads();

    // ---- phase V: Viterbi forward pass on wave 0 (unchanged, proven) ------
    if (j < 64) {
        const int lane = j;

        float trans_col[KK];
        float score = -1e30f;
        if (lane < KK) {
            #pragma unroll
            for (int i = 0; i < KK; i++) trans_col[i] = trans[i * KK + lane];
            score = start_trans[lane] + em_s[lane];
        }

        float em_cur = (lane < KK) ? em_s[KK + lane] : 0.0f;   // t=1
        for (int t = 1; t < TT; t++) {
            float em_next = (t + 1 < TT && lane < KK) ? em_s[(t + 1) * KK + lane] : 0.0f;

            float my = (lane < KK) ? score : -1e30f;
            float cand[KK];
            #pragma unroll
            for (int i = 0; i < KK; i++) cand[i] = __shfl(my, i) + trans_col[i];

            float v01, v23, v45, v67, v03, v47, v07, vb_;
            int   i01, i23, i45, i67, i03, i47, i07, ib_;
            {
                bool gt;
                gt = cand[1] > cand[0]; v01 = gt ? cand[1] : cand[0]; i01 = gt ? 1 : 0;
                gt = cand[3] > cand[2]; v23 = gt ? cand[3] : cand[2]; i23 = gt ? 3 : 2;
                gt = cand[5] > cand[4]; v45 = gt ? cand[5] : cand[4]; i45 = gt ? 5 : 4;
                gt = cand[7] > cand[6]; v67 = gt ? cand[7] : cand[6]; i67 = gt ? 7 : 6;
                gt = v23 > v01; v03 = gt ? v23 : v01; i03 = gt ? i23 : i01;
                gt = v67 > v45; v47 = gt ? v67 : v45; i47 = gt ? i67 : i45;
                gt = v47 > v03; v07 = gt ? v47 : v03; i07 = gt ? i47 : i03;
                gt = cand[8] > v07; vb_ = gt ? cand[8] : v07; ib_ = gt ? 8 : i07;
            }

            if (lane < KK) {
                bp[t][lane] = (unsigned char)ib_;
                score = vb_ + em_cur;
            }
            em_cur = em_next;
        }

        float fin = (lane < KK) ? (score + end_trans[lane]) : -1e30f;
        float farr[KK];
        #pragma unroll
        for (int jx = 0; jx < KK; jx++) farr[jx] = __shfl(fin, jx);
        float v01, v23, v45, v67, v03, v47, v07, vb_;
        int   i01, i23, i45, i67, i03, i47, i07, bj;
        {
            bool gt;
            gt = farr[1] > farr[0]; v01 = gt ? farr[1] : farr[0]; i01 = gt ? 1 : 0;
            gt = farr[3] > farr[2]; v23 = gt ? farr[3] : farr[2]; i23 = gt ? 3 : 2;
            gt = farr[5] > farr[4]; v45 = gt ? farr[5] : farr[4]; i45 = gt ? 5 : 4;
            gt = farr[7] > farr[6]; v67 = gt ? farr[7] : farr[6]; i67 = gt ? 7 : 6;
            gt = v23 > v01; v03 = gt ? v23 : v01; i03 = gt ? i23 : i01;
            gt = v67 > v45; v47 = gt ? v67 : v45; i47 = gt ? i67 : i45;
            gt = v47 > v03; v07 = gt ? v47 : v03; i07 = gt ? i47 : i03;
            gt = farr[8] > v07; vb_ = gt ? farr[8] : v07; bj = gt ? 8 : i07;
        }

        if (lane == 0) {
            bj_s = bj;
            out[b * TT + (TT - 1)] = bj;
        }
    }
    __syncthreads();                     // bp[][] + bj_s visible to all threads

    // ---- parallel backtrack: suffix-compose bp maps (pointer doubling) ----
    {
        unsigned char* mA = (unsigned char*)h_tile;          // [TT][KK]
        unsigned char* mB = mA + TT * KK;
        #pragma unroll
        for (int i = 0; i < KK; i++)
            mA[j * KK + i] = (j >= 1) ? bp[j][i] : (unsigned char)0;
        __syncthreads();
        for (int kk = 1; kk < TT; kk <<= 1) {
            if (j >= 1) {
                if (j + kk < TT) {
                    #pragma unroll
                    for (int i = 0; i < KK; i++)
                        mB[j * KK + i] = mA[j * KK + mA[(j + kk) * KK + i]];
                } else {
                    #pragma unroll
                    for (int i = 0; i < KK; i++)
                        mB[j * KK + i] = mA[j * KK + i];
                }
            }
            __syncthreads();
            unsigned char* tmp = mA; mA = mB; mB = tmp;
        }
        if (j >= 1)
            out[b * TT + (j - 1)] = mA[j * KK + bj_s];
    }
}

// ---------------------------------------------------------------------------
extern "C" void kernel_launch(void* const* d_in, const int* in_sizes, int n_in,
                              void* d_out, int out_size, void* d_ws, size_t ws_size,
                              hipStream_t stream)
{
    const int*   x       = (const int*)  d_in[0];
    const float* emb     = (const float*)d_in[1];
    const float* w_ih_f  = (const float*)d_in[2];
    const float* w_hh_f  = (const float*)d_in[3];
    const float* b_ih_f  = (const float*)d_in[4];
    const float* b_hh_f  = (const float*)d_in[5];
    const float* w_ih_b  = (const float*)d_in[6];
    const float* w_hh_b  = (const float*)d_in[7];
    const float* b_ih_b  = (const float*)d_in[8];
    const float* b_hh_b  = (const float*)d_in[9];
    const float* W_tag   = (const float*)d_in[10];
    const float* b_tag   = (const float*)d_in[11];
    const float* start_t = (const float*)d_in[12];
    const float* end_t   = (const float*)d_in[13];
    const float* trans   = (const float*)d_in[14];
    int* out = (int*)d_out;

    const size_t em_elems    = (size_t)BB * TT * KK;       // 2.25 MB
    const size_t state_elems = (size_t)2 * 128 * 128;
    const size_t hall_elems  = (size_t)2 * BB * TT * 128;  // 67 MB, [dir][b][t][k]

    // C=512 preferred (single dispatch); phase A needs C % 128 == 0.
    int C = 128;
    const int cands[3] = {512, 256, 128};
    for (int ci = 0; ci < 3; ci++) {
        size_t need = ((size_t)2 * cands[ci] * BB * 512
                       + em_elems + 2 * state_elems + hall_elems) * sizeof(float)
                      + 1024;
        if (ws_size >= need) { C = cands[ci]; break; }
    }

    float* buf2    = (float*)d_ws;                        // 2*B*C*512 [dir][b][t][r]
    float* emB     = buf2 + (size_t)2 * C * BB * 512;     // B*T*9
    float* h_state = emB + em_elems;                      // 2*128*128
    float* c_state = h_state + state_elems;               // 2*128*128
    float* h_all   = c_state + state_elems;               // 2*B*T*128
    unsigned* flags = (unsigned*)(h_all + hall_elems);    // 128 monotonic ctrs

    const int rounds = TT / C;
    for (int r = 0; r < rounds; r++) {
        const int t0f = r * C;
        const int t0b = TT - (r + 1) * C;
        lstm_fused<<<dim3(256), dim3(512), 0, stream>>>(
            x, emb, w_ih_f, w_ih_b, b_ih_f, b_hh_f, b_ih_b, b_hh_b,
            buf2, w_hh_f, w_hh_b, h_all,
            h_state, c_state,
            W_tag, b_tag, start_t, end_t, trans,
            emB, flags, out,
            t0f, t0b, C, (r == 0) ? 1 : 0, (r == rounds - 1) ? 1 : 0);
    }
}